// Round 1
// baseline (225.519 us; speedup 1.0000x reference)
//
#include <hip/hip_runtime.h>
#include <hip/hip_bf16.h>

// ConvSelfAttentionModule: B=4, C=256, CQK=128, N=4096 (64x64), fp32 in/out.
// R9: flash-style fusion — never materialize P (was 135 MB write + 135 MB read).
//   k_wcvt   : W -> f16
//   k_xsplit : transpose x[b][c][n] -> xT[b][n][c] f16
//   k_proj   : f16 MFMA GEMM, K=256 single-shot glds staging -> qk, vv (f16)
//   k_rows   : QK^T tiles + exp + partial row sums (NO P write) -> partial
//   k_rsum   : rinv[b][i] = 1 / sum_j exp(S[i,j])
//   k_fav    : fused recompute+AV: per wg (b, 64 j-cols, all 256 c), loop i:
//              S^T tile = K_frags(regs) x Q_tile(LDS, dbuf glds), E'=exp(S)*rinv
//              -> f16 LDS (swizzled) -> acc += V_tile x E'^T; + gamma*.. + x.
//              2 barriers/iter; mid barrier is lgkmcnt-only so the glds
//              prefetch of tile it+1 stays in flight across it (m97 pattern).

typedef _Float16 f16;
typedef _Float16 f16x4v __attribute__((ext_vector_type(4)));
typedef _Float16 f16x8v __attribute__((ext_vector_type(8)));
typedef float f32x4v __attribute__((ext_vector_type(4)));

static __device__ __forceinline__ f32x4v mfma16(f16x8v a, f16x8v b, f32x4v c) {
  // D[m][n]: a-frag m=lane&15,k=quad*8+j; b-frag n=lane&15,k=quad*8+j;
  // D: col(n)=lane&15, row(m)=quad*4+reg
  return __builtin_amdgcn_mfma_f32_16x16x32_f16(a, b, c, 0, 0, 0);
}

#define AS1q __attribute__((address_space(1)))
#define AS3q __attribute__((address_space(3)))
static __device__ __forceinline__ void gl_lds16(const void* g, void* l) {
  // 16B per lane; LDS dest = wave-uniform base + lane*16 (per-lane global src OK)
  __builtin_amdgcn_global_load_lds((const AS1q unsigned int*)g,
                                   (AS3q unsigned int*)l, 16, 0, 0);
}

// ---------------- kernel 0a: weight convert ----------------
__global__ void k_wcvt(const float* __restrict__ wq, const float* __restrict__ bq,
                       const float* __restrict__ wk, const float* __restrict__ bk,
                       const float* __restrict__ wv, const float* __restrict__ bv,
                       f16* __restrict__ wh, float* __restrict__ bcat) {
  int o = blockIdx.x;          // 512 rows: 0-127 q, 128-255 k, 256-511 v
  int c = threadIdx.x;         // 256
  const float* wrow; float bias;
  if (o < 128)      { wrow = wq + (size_t)o * 256;         bias = bq[o]; }
  else if (o < 256) { wrow = wk + (size_t)(o - 128) * 256; bias = bk[o - 128]; }
  else              { wrow = wv + (size_t)(o - 256) * 256; bias = bv[o - 256]; }
  wh[(size_t)o * 256 + c] = (f16)wrow[c];
  if (c == 0) bcat[o] = bias;
}

// ---------------- kernel 0b: x transpose ----------------
// x[b][c][n] f32 -> xT[b][n][c] f16
__global__ void k_xsplit(const float* __restrict__ x, f16* __restrict__ xh) {
  __shared__ float t[64][65];
  int b = blockIdx.z, c0 = blockIdx.y * 64, n0 = blockIdx.x * 64;
  int tx = threadIdx.x & 63, ty = threadIdx.x >> 6;
  const float* xb = x + ((size_t)b * 256 + c0) * 4096 + n0;
#pragma unroll
  for (int r = ty; r < 64; r += 4) t[r][tx] = xb[(size_t)r * 4096 + tx];
  __syncthreads();
  f16* dh = xh + ((size_t)b * 4096 + n0) * 256 + c0;
#pragma unroll
  for (int r = ty; r < 64; r += 4)
    dh[(size_t)r * 256 + tx] = (f16)t[tx][r];
}

// ---------------- kernel 1: projections (f16 NT GEMM, K=256 single-shot) ----------------
// D[i][o] = sum_c xT[i][c]*W[o][c] + b[o];  o<256 -> qk[b][i][o] ; else vv[b][o-256][i]
__global__ void __launch_bounds__(256, 2)
k_proj(const f16* __restrict__ xh, const f16* __restrict__ wh,
       const float* __restrict__ bcat, f16* __restrict__ qk, f16* __restrict__ vv) {
  extern __shared__ char smem[];   // 64KB
  int b = blockIdx.z, m0 = blockIdx.y * 64, n0 = blockIdx.x * 64;
  int tid = threadIdx.x, l = tid & 63, w = tid >> 6;
  int col = l & 15, quad = l >> 4;
  const f16* Ag = xh + ((size_t)b * 4096 + m0) * 256;
  const f16* Wg = wh + (size_t)n0 * 256;
  int rloc = l >> 5;   // row within 1KB chunk (2 rows of 512B)
  int l5 = l & 31;     // 16B group within row
#pragma unroll
  for (int p = 0; p < 8; p++) {
    int ci = w * 8 + p;
    int r = ci * 2 + rloc;
    int g = l5 ^ (r & 31);
    gl_lds16(Ag + (size_t)r * 256 + g * 8, smem + ci * 1024);
    gl_lds16(Wg + (size_t)r * 256 + g * 8, smem + 32768 + ci * 1024);
  }
  __syncthreads();
  const char* sA = smem;
  const char* sW = smem + 32768;
  f32x4v acc[4] = {};
  int ar = w * 16 + col;
#pragma unroll
  for (int ks = 0; ks < 8; ks++) {
    int G = ks * 4 + quad;
    f16x8v a = *(const f16x8v*)(sA + ar * 512 + ((G ^ (ar & 31)) * 16));
#pragma unroll
    for (int nt = 0; nt < 4; nt++) {
      int wr = nt * 16 + col;
      f16x8v bb = *(const f16x8v*)(sW + wr * 512 + ((G ^ (wr & 31)) * 16));
      acc[nt] = mfma16(a, bb, acc[nt]);
    }
  }
  bool isqk = (n0 < 256);  // block-uniform
#pragma unroll
  for (int nt = 0; nt < 4; nt++) {
    int o = n0 + nt * 16 + col;
    float bias = bcat[o];
    if (isqk) {
#pragma unroll
      for (int rg = 0; rg < 4; rg++) {
        int i = m0 + w * 16 + quad * 4 + rg;
        qk[((size_t)b * 4096 + i) * 256 + o] = (f16)(acc[nt][rg] + bias);
      }
    } else {
      int i = m0 + w * 16 + quad * 4;
      f16x4v pv;
#pragma unroll
      for (int rg = 0; rg < 4; rg++) pv[rg] = (f16)(acc[nt][rg] + bias);
      *(f16x4v*)&vv[((size_t)b * 256 + (o - 256)) * 4096 + i] = pv;
    }
  }
}

// ---------------- kernel 2: row sums of exp(S) — NO P write ----------------
// Per block: S for (128 i) x (64 j), K=128 single-shot glds (k_pmake geometry
// minus sPT/P-store). partial[b][jblk][i] = sum over tile's 64 j of exp(s_ij).
__global__ void __launch_bounds__(256, 3)
k_rows(const f16* __restrict__ qk, float* __restrict__ partial) {
  __shared__ char smem[49152];   // sQ [128][128] (32K) + sK [64][128] (16K)
  f16* sQ = (f16*)smem;
  f16* sK = (f16*)(smem + 32768);
  int b = blockIdx.z, i0 = blockIdx.y * 128, j0 = blockIdx.x * 64;
  int tid = threadIdx.x, l = tid & 63, w = tid >> 6;
  int col = l & 15, q = l >> 4;
  const f16* qb = qk + (size_t)b * 4096 * 256;
#pragma unroll
  for (int p = 0; p < 8; p++) {
    int ci = w * 8 + p;
    int r = ci * 4 + (l >> 4);
    int cb = (l & 15) ^ (r & 15);
    gl_lds16(qb + (size_t)(i0 + r) * 256 + cb * 8, smem + ci * 1024);
  }
#pragma unroll
  for (int p = 0; p < 4; p++) {
    int ci = w * 4 + p;
    int r = ci * 4 + (l >> 4);
    int cb = (l & 15) ^ (r & 15);
    gl_lds16(qb + (size_t)(j0 + r) * 256 + 128 + cb * 8, smem + 32768 + ci * 1024);
  }
  __syncthreads();
  f32x4v acc[2][4] = {};
#pragma unroll
  for (int ks = 0; ks < 4; ks++) {
    int phys = (ks * 4 + q) ^ col;
    f16x8v a[2], bb[4];
#pragma unroll
    for (int mt = 0; mt < 2; mt++)
      a[mt] = *(const f16x8v*)&sQ[(w * 32 + mt * 16 + col) * 128 + phys * 8];
#pragma unroll
    for (int nt = 0; nt < 4; nt++)
      bb[nt] = *(const f16x8v*)&sK[(nt * 16 + col) * 128 + phys * 8];
#pragma unroll
    for (int mt = 0; mt < 2; mt++)
#pragma unroll
      for (int nt = 0; nt < 4; nt++)
        acc[mt][nt] = mfma16(a[mt], bb[nt], acc[mt][nt]);
  }
#pragma unroll
  for (int mt = 0; mt < 2; mt++) {
    f32x4v cs;
#pragma unroll
    for (int rg = 0; rg < 4; rg++) {
      float t = __expf(acc[mt][0][rg]) + __expf(acc[mt][1][rg]) +
                __expf(acc[mt][2][rg]) + __expf(acc[mt][3][rg]);
#pragma unroll
      for (int d = 1; d < 16; d <<= 1) t += __shfl_xor(t, d, 64);
      cs[rg] = t;
    }
    if (col == 0) {
      size_t base = ((size_t)b * 64 + blockIdx.x) * 4096 + i0 + w * 32 + mt * 16 + q * 4;
      *(f32x4v*)&partial[base] = cs;
    }
  }
}

// ---------------- kernel 3: combine partials -> rinv = 1/rowsum ----------------
__global__ void k_rsum(const float* __restrict__ partial, float* __restrict__ rinv) {
  int b = blockIdx.y;
  int i = blockIdx.x * 256 + threadIdx.x;
  const float* p = partial + (size_t)b * 64 * 4096 + i;
  float s = 0.f;
#pragma unroll 8
  for (int jb = 0; jb < 64; jb++) s += p[(size_t)jb * 4096];
  rinv[(size_t)b * 4096 + i] = 1.0f / s;
}

// ---------------- kernel 4: fused recompute + AV ----------------
// Per wg: batch b, j-cols [j0,j0+64), all 256 c. Loop i in 64-steps:
//   S^T[j][i] = sum_d K[j,d] Q[i,d]  (K-frags in regs; Q staged LDS dbuf)
//   E'[j][i]  = exp(S)*rinv[i] -> f16 sE (XOR-swizzled)
//   acc[c][j] += V[c][i-tile] x E'^T   (V staged LDS dbuf, f16)
// LDS: sQ 2x16K @0, sV 2x32K @32K, sE 8K @96K = 104 KB -> 1 wg/CU, 8 waves.
__global__ void __launch_bounds__(512, 2)
k_fav(const f16* __restrict__ qk, const f16* __restrict__ vv,
      const float* __restrict__ rinv, const float* __restrict__ x,
      const float* __restrict__ gamma, float* __restrict__ out) {
  extern __shared__ char smem[];  // 104 KB
  f16* sE = (f16*)(smem + 98304);
  // XCD-chunked swizzle: 256 wgs, 8 XCDs -> each XCD runs one contiguous
  // 32-wg slice (= half a batch): per-XCD L2 working set ~4 MB (qk+vv slice).
  int wg = blockIdx.x;
  int lg = (wg & 7) * 32 + (wg >> 3);
  int b = lg >> 6, j0 = (lg & 63) * 64;
  int tid = threadIdx.x, l = tid & 63, w = tid >> 6;
  int col = l & 15, quad = l >> 4;
  int ti = w & 3;            // i-subtile owned in QK phase
  int tjb = (w >> 2) * 2;    // j-subtile pair owned in QK phase
  const f16* qb = qk + (size_t)b * 4096 * 256;
  const f16* vb = vv + (size_t)b * 256 * 4096;
  const float* rp = rinv + (size_t)b * 4096 + ti * 16 + col;

  // --- prologue: stage K rows (j0..j0+63, cols 128..255) into buf0, hoist to regs
#pragma unroll
  for (int p = 0; p < 2; p++) {
    int ci = w * 2 + p;
    int r = ci * 4 + (l >> 4);
    int cb = (l & 15) ^ (r & 15);
    gl_lds16(qb + (size_t)(j0 + r) * 256 + 128 + cb * 8, smem + ci * 1024);
  }
  __syncthreads();
  f16x8v ka[2][4];
  {
    const f16* sK0 = (const f16*)smem;
#pragma unroll
    for (int t = 0; t < 2; t++)
#pragma unroll
      for (int ks = 0; ks < 4; ks++)
        ka[t][ks] = *(const f16x8v*)&sK0[((tjb + t) * 16 + col) * 128 +
                                         (((ks * 4 + quad) ^ col) * 8)];
  }
  __syncthreads();
  // --- stage tile 0 (Q rows 0..63; V cols 0..63) into buf0
#pragma unroll
  for (int p = 0; p < 2; p++) {
    int ci = w * 2 + p;
    int r = ci * 4 + (l >> 4);
    int cb = (l & 15) ^ (r & 15);
    gl_lds16(qb + (size_t)r * 256 + cb * 8, smem + ci * 1024);
  }
#pragma unroll
  for (int p = 0; p < 4; p++) {
    int ci = w * 4 + p;
    int rr = ci * 8 + (l >> 3);
    int g = (l & 7) ^ (rr & 7);
    gl_lds16(vb + (size_t)rr * 4096 + g * 8, smem + 32768 + ci * 1024);
  }

  f32x4v acc[2][4] = {};
  int ig = ti * 2 + (col >> 3);   // logical 8-elem i-group for sE writes
  for (int it = 0; it < 64; it++) {
    int cur = it & 1;
    __syncthreads();   // drains glds of buf[cur] (vmcnt); prev AV reads done
    if (it < 63) {
      int i1 = (it + 1) * 64;
      char* nq = smem + ((it + 1) & 1) * 16384;
      char* nv = smem + 32768 + ((it + 1) & 1) * 32768;
#pragma unroll
      for (int p = 0; p < 2; p++) {
        int ci = w * 2 + p;
        int r = ci * 4 + (l >> 4);
        int cb = (l & 15) ^ (r & 15);
        gl_lds16(qb + (size_t)(i1 + r) * 256 + cb * 8, nq + ci * 1024);
      }
#pragma unroll
      for (int p = 0; p < 4; p++) {
        int ci = w * 4 + p;
        int rr = ci * 8 + (l >> 3);
        int g = (l & 7) ^ (rr & 7);
        gl_lds16(vb + (size_t)rr * 4096 + i1 + g * 8, nv + ci * 1024);
      }
    }
    const f16* sQc = (const f16*)(smem + cur * 16384);
    const f16* sVc = (const f16*)(smem + 32768 + cur * 32768);
    // QK phase: 2 S^T tiles/wave (tj = tjb..tjb+1, i = ti)
    f32x4v accs[2] = {};
#pragma unroll
    for (int ks = 0; ks < 4; ks++) {
      f16x8v qf = *(const f16x8v*)&sQc[(ti * 16 + col) * 128 +
                                       (((ks * 4 + quad) ^ col) * 8)];
      accs[0] = mfma16(ka[0][ks], qf, accs[0]);
      accs[1] = mfma16(ka[1][ks], qf, accs[1]);
    }
    float rv = rp[it * 64];   // rinv for this lane's i (L1/L2-resident)
#pragma unroll
    for (int t = 0; t < 2; t++)
#pragma unroll
      for (int rg = 0; rg < 4; rg++) {
        float e = __expf(accs[t][rg]) * rv;       // E' in [0,1] -> f16 safe
        int jl = (tjb + t) * 16 + quad * 4 + rg;
        sE[jl * 64 + ((ig ^ (jl & 7)) * 8) + (col & 7)] = (f16)e;
      }
    // lgkm-only barrier: sE visible, but buf[cur^1] glds stay in flight
    asm volatile("s_waitcnt lgkmcnt(0)\n\ts_barrier" ::: "memory");
    // AV phase: wave owns c-range [w*32, w*32+32), all 64 j
#pragma unroll
    for (int ks = 0; ks < 2; ks++) {
      int sw = ((ks * 4 + quad) ^ (col & 7)) * 8;
      f16x8v va0 = *(const f16x8v*)&sVc[(w * 32 + col) * 64 + sw];
      f16x8v va1 = *(const f16x8v*)&sVc[(w * 32 + 16 + col) * 64 + sw];
      f16x8v e0 = *(const f16x8v*)&sE[col * 64 + sw];
      f16x8v e1 = *(const f16x8v*)&sE[(16 + col) * 64 + sw];
      f16x8v e2 = *(const f16x8v*)&sE[(32 + col) * 64 + sw];
      f16x8v e3 = *(const f16x8v*)&sE[(48 + col) * 64 + sw];
      acc[0][0] = mfma16(va0, e0, acc[0][0]);
      acc[0][1] = mfma16(va0, e1, acc[0][1]);
      acc[0][2] = mfma16(va0, e2, acc[0][2]);
      acc[0][3] = mfma16(va0, e3, acc[0][3]);
      acc[1][0] = mfma16(va1, e0, acc[1][0]);
      acc[1][1] = mfma16(va1, e1, acc[1][1]);
      acc[1][2] = mfma16(va1, e2, acc[1][2]);
      acc[1][3] = mfma16(va1, e3, acc[1][3]);
    }
  }
  float gm = gamma[0];
  const float* xb = x + (size_t)b * 256 * 4096;
  float* ob = out + (size_t)b * 256 * 4096;
#pragma unroll
  for (int mt = 0; mt < 2; mt++)
#pragma unroll
    for (int jt = 0; jt < 4; jt++) {
      int c = w * 32 + mt * 16 + quad * 4;
      int j = j0 + jt * 16 + col;
#pragma unroll
      for (int rg = 0; rg < 4; rg++) {
        size_t off = (size_t)(c + rg) * 4096 + j;
        ob[off] = gm * acc[mt][jt][rg] + xb[off];
      }
    }
}

extern "C" void kernel_launch(void* const* d_in, const int* in_sizes, int n_in,
                              void* d_out, int out_size, void* d_ws, size_t ws_size,
                              hipStream_t stream) {
  (void)in_sizes; (void)n_in; (void)out_size; (void)ws_size;
  const float* x  = (const float*)d_in[0];
  const float* wq = (const float*)d_in[1];
  const float* bq = (const float*)d_in[2];
  const float* wk = (const float*)d_in[3];
  const float* bk = (const float*)d_in[4];
  const float* wv = (const float*)d_in[5];
  const float* bv = (const float*)d_in[6];
  const float* gm = (const float*)d_in[7];
  float* out = (float*)d_out;

  char* ws = (char*)d_ws;
  f16*  xh = (f16*)ws;                          // 8 MB
  f16*  qk = (f16*)(ws + 8388608);              // 8 MB: [b][i][0:128]=q,[128:256]=k
  f16*  vv = (f16*)(ws + 16777216);             // 8 MB f16 [b][c][i]
  f16*  wh = (f16*)(ws + 25165824);             // 256 KB
  float* bcat    = (float*)(ws + 25427968);     // 2 KB
  float* rinv    = (float*)(ws + 25430016);     // 64 KB
  float* partial = (float*)(ws + 25495552);     // 4 MB: [b][64][4096]

  hipLaunchKernelGGL(k_wcvt, dim3(512), dim3(256), 0, stream, wq, bq, wk, bk, wv, bv, wh, bcat);
  hipLaunchKernelGGL(k_xsplit, dim3(64, 4, 4), dim3(256), 0, stream, x, xh);
  hipLaunchKernelGGL(k_proj, dim3(8, 64, 4), dim3(256), 65536, stream, xh, wh, bcat, qk, vv);
  hipLaunchKernelGGL(k_rows, dim3(64, 32, 4), dim3(256), 0, stream, qk, partial);
  hipLaunchKernelGGL(k_rsum, dim3(16, 4), dim3(256), 0, stream, partial, rinv);
  hipLaunchKernelGGL(k_fav, dim3(256), dim3(512), 106496, stream, qk, vv, rinv, x, gm, out);
}